// Round 1
// baseline (390.904 us; speedup 1.0000x reference)
//
#include <hip/hip_runtime.h>
#include <math.h>

#define EPS 1e-6f
#define DD  256
#define NS  5
#define NQ  8
#define SEQ 13      // NS + NQ
#define KA  8       // anchors per thread in main kernel (N / 256)

// ---------------------------------------------------------------------------
// helpers
// ---------------------------------------------------------------------------
__device__ __forceinline__ void blockReduce2(float& a, float& b, volatile float* f) {
  #pragma unroll
  for (int off = 32; off; off >>= 1) {
    a += __shfl_down(a, off);
    b += __shfl_down(b, off);
  }
  const int wid = threadIdx.x >> 6, lane = threadIdx.x & 63;
  __syncthreads();                 // protect f reuse across calls
  if (lane == 0) { f[wid] = a; f[wid + 4] = b; }
  __syncthreads();
  a = f[0] + f[1] + f[2] + f[3];
  b = f[4] + f[5] + f[6] + f[7];
}

// ---------------------------------------------------------------------------
// kernel 0: zero the two accumulators
// ---------------------------------------------------------------------------
__global__ void proto_zero(float* accum) {
  if (threadIdx.x == 0) { accum[0] = 0.f; accum[1] = 0.f; }
}

// ---------------------------------------------------------------------------
// kernel 1: anchors (transposed), c_a, c_q
//   c_a[n]   = sum(a^2) - 2*eps*sum(a)
//   c_q[i]   = sum(q^2) + 2*eps*sum(q) + D*eps^2
//   logit    = 2*dot(q,a) - c_q - c_a   (matches reference expansion)
// ---------------------------------------------------------------------------
__global__ __launch_bounds__(256) void proto_prep(
    const float* __restrict__ x, float* __restrict__ ca, float* __restrict__ cq,
    float* __restrict__ at, int N) {
  __shared__ float red[8];
  const int n = blockIdx.x, d = threadIdx.x;
  const float* xr = x + (size_t)n * SEQ * DD;

  float a = 0.f;
  #pragma unroll
  for (int s = 0; s < NS; ++s) a += xr[s * DD + d];
  a *= (1.0f / NS);
  at[(size_t)d * N + n] = a;                      // transposed store: AT[d][n]

  float sq = a * a, sm = a;
  blockReduce2(sq, sm, red);
  if (d == 0) ca[n] = sq - 2.0f * EPS * sm;

  for (int s = 0; s < NQ; ++s) {
    float qv  = xr[(NS + s) * DD + d];
    float qsq = qv * qv, qsm = qv;
    blockReduce2(qsq, qsm, red);
    if (d == 0) cq[n * NQ + s] = qsq + 2.0f * EPS * qsm + (float)DD * EPS * EPS;
  }
}

// ---------------------------------------------------------------------------
// kernel 2: fused cross-GEMM + log-softmax-NLL + argmax
// block n handles the 8 query rows of episode n against all N anchors.
// thread tid owns anchors j = tid*KA .. tid*KA+KA-1.
// ---------------------------------------------------------------------------
__global__ __launch_bounds__(256) void proto_main(
    const float* __restrict__ x, const int* __restrict__ label,
    const float* __restrict__ ca, const float* __restrict__ cq,
    const float* __restrict__ at, float* __restrict__ accum, int N) {
  const int n   = blockIdx.x;
  const int tid = threadIdx.x;

  __shared__ __align__(16) float Qs[NQ * DD];   // 8 KB query tile
  __shared__ float red[8];
  __shared__ float sA[4];
  __shared__ int   sI[4];
  __shared__ float s_ll[NQ];

  // stage 8 query rows (contiguous 2048 floats in x)
  {
    const float4* xq = (const float4*)(x + (size_t)(n * SEQ + NS) * DD);
    float4* qs4 = (float4*)Qs;
    #pragma unroll
    for (int i = tid; i < NQ * DD / 4; i += 256) qs4[i] = xq[i];
  }
  __syncthreads();

  float acc[NQ][KA];
  #pragma unroll
  for (int s = 0; s < NQ; ++s)
    #pragma unroll
    for (int k = 0; k < KA; ++k) acc[s][k] = 0.f;

  const float* atp = at + (size_t)tid * KA;
  for (int d0 = 0; d0 < DD; d0 += 4) {
    float av[4][KA];
    #pragma unroll
    for (int dd = 0; dd < 4; ++dd) {
      const float4* p = (const float4*)(atp + (size_t)(d0 + dd) * N);
      float4 v0 = p[0], v1 = p[1];
      av[dd][0] = v0.x; av[dd][1] = v0.y; av[dd][2] = v0.z; av[dd][3] = v0.w;
      av[dd][4] = v1.x; av[dd][5] = v1.y; av[dd][6] = v1.z; av[dd][7] = v1.w;
    }
    #pragma unroll
    for (int s = 0; s < NQ; ++s) {
      float4 qv = *(const float4*)&Qs[s * DD + d0];
      float q[4] = {qv.x, qv.y, qv.z, qv.w};
      #pragma unroll
      for (int dd = 0; dd < 4; ++dd)
        #pragma unroll
        for (int k = 0; k < KA; ++k)
          acc[s][k] = fmaf(q[dd], av[dd][k], acc[s][k]);
    }
  }

  // per-thread anchor constants
  float cav[KA];
  {
    const float4* p = (const float4*)(ca + (size_t)tid * KA);
    float4 v0 = p[0], v1 = p[1];
    cav[0] = v0.x; cav[1] = v0.y; cav[2] = v0.z; cav[3] = v0.w;
    cav[4] = v1.x; cav[5] = v1.y; cav[6] = v1.z; cav[7] = v1.w;
  }

  const int lab   = label[n];
  const int lab_t = lab >> 3, lab_k = lab & 7;

  float lossacc = 0.f, corr = 0.f;
  #pragma unroll 1
  for (int s = 0; s < NQ; ++s) {
    const float cqv = cq[n * NQ + s];
    float lg[KA];
    float m = -1e30f;
    int   mi = 0x7fffffff;
    #pragma unroll
    for (int k = 0; k < KA; ++k) {
      float v = 2.0f * acc[s][k] - cav[k] - cqv;
      lg[k] = v;
      if (v > m) { m = v; mi = tid * KA + k; }   // strict > keeps lowest index on ties
    }
    if (tid == lab_t) s_ll[s] = lg[lab_k];

    // block argmax (lowest index wins ties, matching jnp.argmax)
    #pragma unroll
    for (int off = 32; off; off >>= 1) {
      float om = __shfl_down(m, off);
      int   oi = __shfl_down(mi, off);
      if (om > m || (om == m && oi < mi)) { m = om; mi = oi; }
    }
    const int wid = tid >> 6, lane = tid & 63;
    __syncthreads();
    if (lane == 0) { sA[wid] = m; sI[wid] = mi; }
    __syncthreads();
    m = sA[0]; mi = sI[0];
    #pragma unroll
    for (int w = 1; w < 4; ++w) {
      float om = sA[w]; int oi = sI[w];
      if (om > m || (om == m && oi < mi)) { m = om; mi = oi; }
    }

    // sum of exp(logit - m)
    float se = 0.f;
    #pragma unroll
    for (int k = 0; k < KA; ++k) se += expf(lg[k] - m);
    #pragma unroll
    for (int off = 32; off; off >>= 1) se += __shfl_down(se, off);
    __syncthreads();
    if (lane == 0) red[wid] = se;
    __syncthreads();
    se = red[0] + red[1] + red[2] + red[3];

    lossacc += m + logf(se) - s_ll[s];
    corr    += (mi == lab) ? 1.0f : 0.0f;
  }

  if (tid == 0) {
    atomicAdd(&accum[0], lossacc);
    atomicAdd(&accum[1], corr);
  }
}

// ---------------------------------------------------------------------------
// kernel 3: finalize
// ---------------------------------------------------------------------------
__global__ void proto_fin(const float* __restrict__ accum, float* __restrict__ out, int M) {
  if (threadIdx.x == 0) {
    out[0] = accum[0] / (float)M;
    out[1] = accum[1] * 100.0f / (float)M;
  }
}

// ---------------------------------------------------------------------------
extern "C" void kernel_launch(void* const* d_in, const int* in_sizes, int n_in,
                              void* d_out, int out_size, void* d_ws, size_t ws_size,
                              hipStream_t stream) {
  const float* x     = (const float*)d_in[0];
  const int*   label = (const int*)d_in[1];
  const int N = in_sizes[1];          // 2048
  float* out = (float*)d_out;

  // ws layout (floats): [0:2) accum | [16:16+N) c_a | [16+N : 16+N+N*NQ) c_q | AT (D*N)
  float* W     = (float*)d_ws;
  float* accum = W;
  float* ca    = W + 16;
  float* cq    = ca + N;
  size_t atoff = (size_t)16 + N + (size_t)N * NQ;
  atoff = (atoff + 3) & ~(size_t)3;   // 16B-align for float4
  float* at    = W + atoff;

  hipLaunchKernelGGL(proto_zero, dim3(1),  dim3(64),  0, stream, accum);
  hipLaunchKernelGGL(proto_prep, dim3(N),  dim3(256), 0, stream, x, ca, cq, at, N);
  hipLaunchKernelGGL(proto_main, dim3(N),  dim3(256), 0, stream, x, label, ca, cq, at, accum, N);
  hipLaunchKernelGGL(proto_fin,  dim3(1),  dim3(64),  0, stream, accum, out, N * NQ);
}

// Round 2
// 162.428 us; speedup vs baseline: 2.4066x; 2.4066x over previous
//
#include <hip/hip_runtime.h>
#include <math.h>

#define EPS  1e-6f
#define DD   256
#define NSUP 5
#define NQ   8
#define SEQ  13
#define L2E  1.44269504088896f

typedef short bf16x8 __attribute__((ext_vector_type(8)));
typedef float f32x4  __attribute__((ext_vector_type(4)));

__device__ __forceinline__ ushort f2bf(float f) {
  union { float f; unsigned u; } v; v.f = f;
  unsigned r = v.u + 0x7FFFu + ((v.u >> 16) & 1u);   // round-to-nearest-even
  return (ushort)(r >> 16);
}

// ---------------------------------------------------------------------------
// prep: bf16 anchors (mean of 5 supports) + bf16 queries + fp32 constants.
//   ca[n] = sum(a^2) - 2*eps*sum(a)
//   cq[i] = sum(q^2) + 2*eps*sum(q) + D*eps^2
//   logit = 2*dot(q,a) - cq - ca  (matches reference expansion exactly)
// Also zeroes the global accumulator (ws is re-poisoned before every call).
// ---------------------------------------------------------------------------
__global__ __launch_bounds__(256) void proto_prep(
    const float* __restrict__ x, float* __restrict__ ca, float* __restrict__ cq,
    ushort* __restrict__ Abf, ushort* __restrict__ Qbf, float* accum) {
  const int n = blockIdx.x, d = threadIdx.x;
  if (n == 0 && d == 0) { accum[0] = 0.f; accum[1] = 0.f; }
  const float* xr = x + (size_t)n * SEQ * DD;

  float vals[9];
  float a = 0.f;
  #pragma unroll
  for (int s = 0; s < NSUP; ++s) a += xr[s * DD + d];
  a *= 0.2f;
  Abf[(size_t)n * DD + d] = f2bf(a);
  vals[0] = a;
  #pragma unroll
  for (int s = 0; s < NQ; ++s) {
    float q = xr[(NSUP + s) * DD + d];
    Qbf[((size_t)n * NQ + s) * DD + d] = f2bf(q);
    vals[1 + s] = q;
  }

  __shared__ float part[4][9][2];
  const int wid = d >> 6, lane = d & 63;
  #pragma unroll
  for (int r = 0; r < 9; ++r) {
    float s1 = vals[r], s2 = vals[r] * vals[r];
    #pragma unroll
    for (int off = 32; off; off >>= 1) {
      s1 += __shfl_xor(s1, off);
      s2 += __shfl_xor(s2, off);
    }
    if (lane == 0) { part[wid][r][0] = s1; part[wid][r][1] = s2; }
  }
  __syncthreads();
  if (d < 9) {
    float s1 = part[0][d][0] + part[1][d][0] + part[2][d][0] + part[3][d][0];
    float s2 = part[0][d][1] + part[1][d][1] + part[2][d][1] + part[3][d][1];
    if (d == 0) ca[n] = s2 - 2.f * EPS * s1;
    else        cq[n * NQ + (d - 1)] = s2 + 2.f * EPS * s1 + (float)DD * EPS * EPS;
  }
}

// ---------------------------------------------------------------------------
// main: bf16 MFMA cross-GEMM fused with online log-softmax + argmax.
// Block = 32 query rows (4 episodes), 4 waves; wave w owns col stripe
// [w*N/4, (w+1)*N/4). Each wave: two 16-row A-frag sets share every B-frag
// (2 MFMAs per B load -> halves fragment traffic). Online (m, sumexp, argmax,
// label-logit) per MFMA C-slot; shfl_xor merge over the 16-lane col group;
// LDS merge across the 4 waves; one atomicAdd pair per block.
// MFMA layouts (verified per guide): A m=lane&15,k=quad*8+j ; B n=lane&15,
// k=quad*8+j ; C col=lane&15,row=quad*4+reg.
// ---------------------------------------------------------------------------
__global__ __launch_bounds__(256, 2) void proto_main(
    const ushort* __restrict__ Qbf, const ushort* __restrict__ Abf,
    const float* __restrict__ ca, const float* __restrict__ cq,
    const int* __restrict__ label, float* __restrict__ accum, int N) {
  const int tid  = threadIdx.x;
  const int wid  = tid >> 6, lane = tid & 63;
  const int quad = lane >> 4, lcol = lane & 15;
  const int r0   = blockIdx.x * 32;
  const int col0 = wid * (N >> 2);

  // A fragments: 2 sets x 8 K-chunks, resident for the whole kernel
  bf16x8 af[2][8];
  #pragma unroll
  for (int set = 0; set < 2; ++set) {
    const ushort* qp = Qbf + (size_t)(r0 + set * 16 + lcol) * DD + quad * 8;
    #pragma unroll
    for (int kk = 0; kk < 8; ++kk) af[set][kk] = *(const bf16x8*)(qp + kk * 32);
  }

  // per-slot row constants + online state (rows fixed per lane for all tiles)
  float cqv[2][4], m[2][4], ssum[2][4], ll[2][4];
  int   lab[2][4], bi[2][4];
  #pragma unroll
  for (int set = 0; set < 2; ++set)
    #pragma unroll
    for (int i = 0; i < 4; ++i) {
      int row = r0 + set * 16 + quad * 4 + i;
      cqv[set][i] = cq[row];
      lab[set][i] = label[row >> 3];
      m[set][i] = -1e30f; ssum[set][i] = 0.f; ll[set][i] = 0.f;
      bi[set][i] = 0x7fffffff;
    }

  const int ntiles = (N >> 2) >> 4;
  for (int t = 0; t < ntiles; ++t) {
    const int colIdx = col0 + t * 16 + lcol;
    const ushort* bp = Abf + (size_t)colIdx * DD + quad * 8;
    f32x4 c0 = {0.f, 0.f, 0.f, 0.f}, c1 = {0.f, 0.f, 0.f, 0.f};
    #pragma unroll
    for (int kk = 0; kk < 8; ++kk) {
      bf16x8 b = *(const bf16x8*)(bp + kk * 32);
      c0 = __builtin_amdgcn_mfma_f32_16x16x32_bf16(af[0][kk], b, c0, 0, 0, 0);
      c1 = __builtin_amdgcn_mfma_f32_16x16x32_bf16(af[1][kk], b, c1, 0, 0, 0);
    }
    const float cav = ca[colIdx];
    #pragma unroll
    for (int set = 0; set < 2; ++set) {
      #pragma unroll
      for (int i = 0; i < 4; ++i) {
        float cv = (set == 0) ? c0[i] : c1[i];
        float v  = 2.f * cv - cav - cqv[set][i];
        float om = m[set][i];
        float nm = fmaxf(om, v);
        ssum[set][i] = ssum[set][i] * exp2f((om - nm) * L2E) + exp2f((v - nm) * L2E);
        bi[set][i]   = (v > om) ? colIdx : bi[set][i];   // strict >: first max wins
        m[set][i]    = nm;
        ll[set][i]   = (colIdx == lab[set][i]) ? v : ll[set][i];
      }
    }
  }

  // merge across the 16 lanes sharing the same rows (cols differ)
  #pragma unroll
  for (int mask = 1; mask < 16; mask <<= 1) {
    #pragma unroll
    for (int set = 0; set < 2; ++set)
      #pragma unroll
      for (int i = 0; i < 4; ++i) {
        float om = __shfl_xor(m[set][i], mask);
        float os = __shfl_xor(ssum[set][i], mask);
        int   oi = __shfl_xor(bi[set][i], mask);
        float ol = __shfl_xor(ll[set][i], mask);
        float nm = fmaxf(m[set][i], om);
        ssum[set][i] = ssum[set][i] * exp2f((m[set][i] - nm) * L2E)
                     + os * exp2f((om - nm) * L2E);
        bool better = (om > m[set][i]) || (om == m[set][i] && oi < bi[set][i]);
        bi[set][i] = better ? oi : bi[set][i];
        m[set][i]  = nm;
        ll[set][i] += ol;          // exactly one slot holds the label logit
      }
  }

  __shared__ float sm[4][32], ssh[4][32], sll[4][32];
  __shared__ int   sbi[4][32];
  if (lcol == 0) {
    #pragma unroll
    for (int set = 0; set < 2; ++set)
      #pragma unroll
      for (int i = 0; i < 4; ++i) {
        int rl = set * 16 + quad * 4 + i;
        sm[wid][rl] = m[set][i]; ssh[wid][rl] = ssum[set][i];
        sll[wid][rl] = ll[set][i]; sbi[wid][rl] = bi[set][i];
      }
  }
  __syncthreads();
  if (tid < 32) {
    float mm = sm[0][tid], s = ssh[0][tid], l = sll[0][tid];
    int   b  = sbi[0][tid];
    #pragma unroll
    for (int w = 1; w < 4; ++w) {          // stripes in ascending col order
      float om = sm[w][tid], os = ssh[w][tid];
      int   oi = sbi[w][tid];
      float nm = fmaxf(mm, om);
      s = s * exp2f((mm - nm) * L2E) + os * exp2f((om - nm) * L2E);
      bool better = (om > mm) || (om == mm && oi < b);
      b = better ? oi : b;
      mm = nm;
      l += sll[w][tid];
    }
    int   row  = r0 + tid;
    int   lb   = label[row >> 3];
    float loss = mm + logf(s) - l;
    float corr = (b == lb) ? 1.f : 0.f;
    #pragma unroll
    for (int mask = 16; mask; mask >>= 1) {
      loss += __shfl_xor(loss, mask);
      corr += __shfl_xor(corr, mask);
    }
    if (tid == 0) { atomicAdd(&accum[0], loss); atomicAdd(&accum[1], corr); }
  }
}

// ---------------------------------------------------------------------------
__global__ void proto_fin(const float* __restrict__ accum, float* __restrict__ out, int M) {
  if (threadIdx.x == 0) {
    out[0] = accum[0] / (float)M;
    out[1] = accum[1] * 100.0f / (float)M;
  }
}

// ---------------------------------------------------------------------------
extern "C" void kernel_launch(void* const* d_in, const int* in_sizes, int n_in,
                              void* d_out, int out_size, void* d_ws, size_t ws_size,
                              hipStream_t stream) {
  const float* x     = (const float*)d_in[0];
  const int*   label = (const int*)d_in[1];
  const int N = in_sizes[1];               // 2048 episodes
  float* out = (float*)d_out;

  // ws layout (floats): [0:2) accum | [16,16+N) ca | [16+N,16+9N) cq |
  //                     Abf (N*DD bf16) | Qbf (N*NQ*DD bf16)
  float*  W     = (float*)d_ws;
  float*  accum = W;
  float*  ca    = W + 16;
  float*  cq    = ca + N;
  ushort* Abf   = (ushort*)(W + 16 + 9 * (size_t)N);      // 16B-aligned
  ushort* Qbf   = Abf + (size_t)N * DD;

  hipLaunchKernelGGL(proto_prep, dim3(N), dim3(256), 0, stream,
                     x, ca, cq, Abf, Qbf, accum);
  hipLaunchKernelGGL(proto_main, dim3((N * NQ) / 32), dim3(256), 0, stream,
                     Qbf, Abf, ca, cq, label, accum, N);
  hipLaunchKernelGGL(proto_fin, dim3(1), dim3(64), 0, stream, accum, out, N * NQ);
}